// Round 2
// baseline (14578.862 us; speedup 1.0000x reference)
//
#include <hip/hip_runtime.h>

typedef unsigned short u16;
typedef __attribute__((ext_vector_type(8))) short short8;
typedef __attribute__((ext_vector_type(4))) float f32x4;

#define NN 307      // nodes
#define NP 320      // padded nodes
#define TT 64       // time steps
#define NB 64       // batch
#define LDP 68      // ldsG row stride (f32): 68*4=272B, 16B-aligned
#define LNEPS 1e-5f

__device__ __forceinline__ u16 f2bf(float f) {
  union { float f; unsigned u; } v; v.f = f;
  unsigned r = (v.u + 0x7FFFu + ((v.u >> 16) & 1u)) >> 16;  // RNE
  return (u16)r;
}
__device__ __forceinline__ float bf2f(u16 h) {
  union { unsigned u; float f; } v; v.u = ((unsigned)h) << 16;
  return v.f;
}
__device__ __forceinline__ void split3(float v, u16 &h, u16 &m, u16 &l) {
  h = f2bf(v);
  float r1 = v - bf2f(h);
  m = f2bf(r1);
  float r2 = r1 - bf2f(m);
  l = f2bf(r2);
}

#define MFMA(a, b, c) __builtin_amdgcn_mfma_f32_16x16x32_bf16((a), (b), (c), 0, 0, 0)

// ---------------------------------------------------------------------------
// prep: A -> 3x bf16 splits (zero-padded 320x320); fold Wf = W_obs @ Wg_bot.
// (identical to the verified v0 kernel)
// ---------------------------------------------------------------------------
__global__ __launch_bounds__(256) void k_prep(
    const float* __restrict__ A, const float* __restrict__ W_obs,
    const float* __restrict__ b_obs, const float* __restrict__ W_gate,
    u16* __restrict__ A_hi, u16* __restrict__ A_md, u16* __restrict__ A_lo,
    float* __restrict__ Wf, float* __restrict__ bfold)
{
  if (blockIdx.x < 400) {
    const int e = blockIdx.x * 256 + threadIdx.x;
    const int r = e / NP, c = e - r * NP;
    const float a = (r < NN && c < NN) ? A[r * NN + c] : 0.f;
    u16 h, m, l;
    split3(a, h, m, l);
    A_hi[e] = h; A_md[e] = m; A_lo[e] = l;
  } else if (threadIdx.x < 64) {
    const int dp = threadIdx.x;
    float s0 = 0.f, s1 = 0.f, s2 = 0.f, sb = 0.f;
    for (int d = 0; d < 64; ++d) {
      const float wg = W_gate[(64 + d) * 64 + dp];
      s0 += W_obs[d] * wg;
      s1 += W_obs[64 + d] * wg;
      s2 += W_obs[128 + d] * wg;
      sb += b_obs[d] * wg;
    }
    Wf[dp] = s0; Wf[64 + dp] = s1; Wf[128 + dp] = s2; bfold[dp] = sb;
  }
}

// ---------------------------------------------------------------------------
// GEMM stage (per block = one batch b): acc[n-tile] = X(64xK) * Amat(320xK)^T
// then scatter to ldsG as fp32 [n][d] with quad XOR swizzle.
// 8 waves: cr = w&3 picks the 16 c-rows (d-dim), (w>>2) picks n half (160).
// Same MFMA fragment conventions as verified v0 (m89 C/D layout).
// ---------------------------------------------------------------------------
__device__ __forceinline__ void gemm_stage(
    const u16* __restrict__ Xh, const u16* __restrict__ Xm, const u16* __restrict__ Xl,
    const u16* __restrict__ Ah, const u16* __restrict__ Am, const u16* __restrict__ Al,
    int b, int cr, int g160, int lr, int lg, float* ldsG)
{
  const size_t xbase = (size_t)(b * 64 + cr * 16 + lr) * NP;
  f32x4 acc[10];
#pragma unroll
  for (int i = 0; i < 10; ++i) acc[i] = (f32x4){0.f, 0.f, 0.f, 0.f};
  unsigned abase[10];
#pragma unroll
  for (int i = 0; i < 10; ++i) abase[i] = (unsigned)((g160 + i * 16 + lr) * NP);

  for (int kk = 0; kk < 10; ++kk) {
    const int ko = kk * 32 + lg * 8;
    const short8 xh = *(const short8*)&Xh[xbase + ko];
    const short8 xm = *(const short8*)&Xm[xbase + ko];
    const short8 xl = *(const short8*)&Xl[xbase + ko];
#pragma unroll
    for (int i = 0; i < 10; ++i) {
      const short8 ah = *(const short8*)&Ah[abase[i] + ko];
      const short8 am = *(const short8*)&Am[abase[i] + ko];
      const short8 al = *(const short8*)&Al[abase[i] + ko];
      f32x4 a = acc[i];
      a = MFMA(xh, ah, a);   // hi*hi
      a = MFMA(xh, am, a);   // hi*md
      a = MFMA(xm, ah, a);   // md*hi
      a = MFMA(xh, al, a);   // hi*lo
      a = MFMA(xl, ah, a);   // lo*hi
      a = MFMA(xm, am, a);   // md*md
      acc[i] = a;
    }
  }
#pragma unroll
  for (int i = 0; i < 10; ++i) {
    const int n = g160 + i * 16 + lr;
    const int q = cr * 4 + lg;
    *(f32x4*)&ldsG[n * LDP + ((q ^ (n & 15)) << 2)] = acc[i];
  }
}

// o[i][c] = sum_d ldsG[n_i][d] * ldsW[d][dq*4+c], n_i = nset + 32*i (fp32 exact)
__device__ __forceinline__ void mat64b(const float* __restrict__ ldsG,
                                       const float* __restrict__ ldsW,
                                       int nset, int dq, float o[10][4])
{
#pragma unroll
  for (int i = 0; i < 10; ++i)
#pragma unroll
    for (int c = 0; c < 4; ++c) o[i][c] = 0.f;
  const int nq15 = nset & 15;
  for (int d4 = 0; d4 < 16; ++d4) {
    f32x4 wv[4];
#pragma unroll
    for (int m = 0; m < 4; ++m)
      wv[m] = *(const f32x4*)&ldsW[(d4 * 4 + m) * 64 + dq * 4];
#pragma unroll
    for (int i = 0; i < 10; ++i) {
      const f32x4 gr = *(const f32x4*)&ldsG[(nset + 32 * i) * LDP + ((d4 ^ nq15) << 2)];
#pragma unroll
      for (int m = 0; m < 4; ++m) {
        const float g = gr[m];
#pragma unroll
        for (int c = 0; c < 4; ++c) o[i][c] += g * wv[m][c];
      }
    }
  }
}

// ---------------------------------------------------------------------------
// Persistent per-batch kernel: the whole 63-step scan for batch b in one
// block. State z is fp32 in registers (zf[10][4] per thread); bf16 splits of
// z/h round-trip through global, which stays XCD-L2-resident (b-local,
// ~250KB/batch). Weights live in LDS for the whole kernel. No grid syncs:
// the recurrence never crosses b.
// ---------------------------------------------------------------------------
__global__ __launch_bounds__(512, 1) void k_main(
    const float* __restrict__ x_seq, const float* __restrict__ obs_mask,
    const float* __restrict__ W_enc, const float* __restrict__ b_enc,
    const float* __restrict__ ln_g, const float* __restrict__ ln_b,
    const float* __restrict__ W_obs, const float* __restrict__ b_obs,
    const float* __restrict__ W_gate, const float* __restrict__ b_gate,
    const float* __restrict__ W_dec, const float* __restrict__ b_dec,
    const float* __restrict__ W_gc1, const float* __restrict__ W_gc2,
    const float* __restrict__ Wf, const float* __restrict__ bfold,
    const u16* __restrict__ A_hi, const u16* __restrict__ A_md, const u16* __restrict__ A_lo,
    u16* __restrict__ Z_hi, u16* __restrict__ Z_md, u16* __restrict__ Z_lo,
    u16* __restrict__ H_hi, u16* __restrict__ H_md, u16* __restrict__ H_lo,
    float* __restrict__ out)
{
  const int b = blockIdx.x;
  const int tid = threadIdx.x;
  const int w = tid >> 6, l = tid & 63, lr = l & 15, lg = l >> 4;
  const int dq = tid & 15, nset = tid >> 4;        // epilogue slot: (n = nset+32i, d' = dq*4+c)
  const int cr = w & 3, g160 = (w >> 2) * 160;     // GEMM wave role

  __shared__ __align__(16) float ldsG[NP * LDP];               // 87040 B
  __shared__ __align__(16) float ldsW1[64 * 64];               // 16 KB
  __shared__ __align__(16) float ldsW2[64 * 64];
  __shared__ __align__(16) float ldsWg[64 * 64];
  __shared__ float sXv[NP * 4];
  __shared__ float sMask[NP];
  __shared__ float sWo[192], sWfl[192], sWe[192];
  __shared__ float sBe[64], sLng[64], sLnb[64], sWd[64], sBg[64], sBo[64], sBf[64];

  // ---- one-time staging ----
#pragma unroll
  for (int j = 0; j < 8; ++j) {
    ldsW1[tid * 8 + j] = W_gc1[tid * 8 + j];
    ldsW2[tid * 8 + j] = W_gc2[tid * 8 + j];
    ldsWg[tid * 8 + j] = W_gate[tid * 8 + j];   // rows 0..63 = Wg_top
  }
  if (tid < 192) { sWo[tid] = W_obs[tid]; sWfl[tid] = Wf[tid]; sWe[tid] = W_enc[tid]; }
  else if (tid < 256) {
    const int d = tid - 192;
    sBe[d] = b_enc[d]; sLng[d] = ln_g[d]; sLnb[d] = ln_b[d]; sWd[d] = W_dec[d];
    sBg[d] = b_gate[d]; sBo[d] = b_obs[d]; sBf[d] = bfold[d];
  }
  if (tid < NP) {
    const int n = tid;
    sMask[n] = (n < NN) ? obs_mask[b * NN + n] : 0.f;
    float x0 = 0.f, x1 = 0.f, x2 = 0.f;
    if (n < NN) {
      const size_t xo = ((size_t)(b * NN + n) * TT) * 3;
      x0 = x_seq[xo]; x1 = x_seq[xo + 1]; x2 = x_seq[xo + 2];
    }
    sXv[n * 4] = x0; sXv[n * 4 + 1] = x1; sXv[n * 4 + 2] = x2; sXv[n * 4 + 3] = 0.f;
  }
  const float bdec = b_dec[0];
  __syncthreads();

  // ---- init: z0 = x0 @ W_enc + b_enc ; splits ; pred col 0 ----
  float zf[10][4];
#pragma unroll
  for (int i = 0; i < 10; ++i) {
    const int n = nset + 32 * i;
    const bool valid = n < NN;
    const float x0 = sXv[n * 4], x1 = sXv[n * 4 + 1], x2 = sXv[n * 4 + 2];
    float p = 0.f;
#pragma unroll
    for (int c = 0; c < 4; ++c) {
      const int dpp = dq * 4 + c;
      float z = x0 * sWe[dpp] + x1 * sWe[64 + dpp] + x2 * sWe[128 + dpp] + sBe[dpp];
      z = valid ? z : 0.f;
      zf[i][c] = z;
      u16 hh, mm, ll; split3(z, hh, mm, ll);
      const size_t off = (size_t)(b * 64 + dpp) * NP + n;
      Z_hi[off] = hh; Z_md[off] = mm; Z_lo[off] = ll;
      p += z * sWd[dpp];
    }
#pragma unroll
    for (int m = 1; m < 16; m <<= 1) p += __shfl_xor(p, m, 64);
    if (dq == 0 && valid) out[(size_t)(b * NN + n) * TT] = p + bdec;
  }
  __syncthreads();   // drains z-split stores to L2 before stage1 reads

  // ---- 63 scan steps, all in-block ----
  for (int t = 0; t < 63; ++t) {
    // stage 1: h1 = tanh((A@z)@W_gc1) -> global splits (L2-resident)
    float px0 = 0.f, px1 = 0.f, px2 = 0.f;
    if (tid < NN) {        // prefetch x_{t+1}; latency hidden under the GEMM
      const size_t xo = ((size_t)(b * NN + tid) * TT + (t + 1)) * 3;
      px0 = x_seq[xo]; px1 = x_seq[xo + 1]; px2 = x_seq[xo + 2];
    }
    gemm_stage(Z_hi, Z_md, Z_lo, A_hi, A_md, A_lo, b, cr, g160, lr, lg, ldsG);
    if (tid < NP) {
      sXv[tid * 4] = px0; sXv[tid * 4 + 1] = px1; sXv[tid * 4 + 2] = px2;
    }
    __syncthreads();
    {
      float o[10][4];
      mat64b(ldsG, ldsW1, nset, dq, o);
#pragma unroll
      for (int i = 0; i < 10; ++i) {
        const int n = nset + 32 * i;
#pragma unroll
        for (int c = 0; c < 4; ++c) {
          const float h = tanhf(o[i][c]);      // pad nodes: A rows zeroed -> h = 0
          u16 hh, mm, ll; split3(h, hh, mm, ll);
          const size_t off = (size_t)(b * 64 + dq * 4 + c) * NP + n;
          H_hi[off] = hh; H_md[off] = mm; H_lo[off] = ll;
        }
      }
    }
    __syncthreads();   // drains h-split stores; frees ldsG

    // stage 2: h2 = tanh((A@h1)@W_gc2); delta = LN; z' = 2z+delta;
    // gate = sigmoid(z'@Wg_top + x@Wf + bfold + b_gate); update; pred
    gemm_stage(H_hi, H_md, H_lo, A_hi, A_md, A_lo, b, cr, g160, lr, lg, ldsG);
    __syncthreads();
    {
      float o[10][4];
      mat64b(ldsG, ldsW2, nset, dq, o);
      float zp[10][4];
      const int nq15 = nset & 15;
#pragma unroll
      for (int i = 0; i < 10; ++i) {
        float h2[4];
#pragma unroll
        for (int c = 0; c < 4; ++c) h2[c] = tanhf(o[i][c]);
        float s = h2[0] + h2[1] + h2[2] + h2[3];
#pragma unroll
        for (int m = 1; m < 16; m <<= 1) s += __shfl_xor(s, m, 64);
        const float mu = s * (1.f / 64.f);
        float q = 0.f;
#pragma unroll
        for (int c = 0; c < 4; ++c) { const float d0 = h2[c] - mu; q += d0 * d0; }
#pragma unroll
        for (int m = 1; m < 16; m <<= 1) q += __shfl_xor(q, m, 64);
        const float rs = rsqrtf(q * (1.f / 64.f) + LNEPS);
#pragma unroll
        for (int c = 0; c < 4; ++c) {
          const int dpp = dq * 4 + c;
          const float delta = (h2[c] - mu) * rs * sLng[dpp] + sLnb[dpp];
          zp[i][c] = 2.f * zf[i][c] + delta;
        }
        // z' row n is only ever read by this 16-lane group (same wave):
        // no barrier needed for the LDS round-trip.
        f32x4 zrow = { zp[i][0], zp[i][1], zp[i][2], zp[i][3] };
        *(f32x4*)&ldsG[(nset + 32 * i) * LDP + ((dq ^ nq15) << 2)] = zrow;
      }
      float ps[10][4];
      mat64b(ldsG, ldsWg, nset, dq, ps);
#pragma unroll
      for (int i = 0; i < 10; ++i) {
        const int n = nset + 32 * i;
        const bool valid = n < NN;
        const float x0 = sXv[n * 4], x1 = sXv[n * 4 + 1], x2 = sXv[n * 4 + 2];
        const float mk = sMask[n];
        float p = 0.f;
#pragma unroll
        for (int c = 0; c < 4; ++c) {
          const int dpp = dq * 4 + c;
          const float presig = ps[i][c] + sBg[dpp] + sBf[dpp]
              + x0 * sWfl[dpp] + x1 * sWfl[64 + dpp] + x2 * sWfl[128 + dpp];
          const float gate = 1.f / (1.f + expf(-presig));
          const float zobs = x0 * sWo[dpp] + x1 * sWo[64 + dpp] + x2 * sWo[128 + dpp] + sBo[dpp];
          float zn = zp[i][c] + gate * (zobs - zp[i][c]) * mk;
          zn = valid ? zn : 0.f;
          zf[i][c] = zn;
          u16 hh, mm, ll; split3(zn, hh, mm, ll);
          const size_t off = (size_t)(b * 64 + dpp) * NP + n;
          Z_hi[off] = hh; Z_md[off] = mm; Z_lo[off] = ll;
          p += zn * sWd[dpp];
        }
#pragma unroll
        for (int m = 1; m < 16; m <<= 1) p += __shfl_xor(p, m, 64);
        if (dq == 0 && valid) out[(size_t)(b * NN + n) * TT + (t + 1)] = p + bdec;
      }
    }
    __syncthreads();   // drains z-split stores; frees ldsG/sXv for next step
  }
}

// ---------------------------------------------------------------------------
extern "C" void kernel_launch(void* const* d_in, const int* in_sizes, int n_in,
                              void* d_out, int out_size, void* d_ws, size_t ws_size,
                              hipStream_t stream) {
  const float* x_seq  = (const float*)d_in[0];
  const float* obs    = (const float*)d_in[1];
  const float* A      = (const float*)d_in[2];
  const float* W_enc  = (const float*)d_in[3];
  const float* b_enc  = (const float*)d_in[4];
  const float* W_gc1  = (const float*)d_in[5];
  const float* W_gc2  = (const float*)d_in[6];
  const float* ln_g   = (const float*)d_in[7];
  const float* ln_b   = (const float*)d_in[8];
  const float* W_obs  = (const float*)d_in[9];
  const float* b_obs  = (const float*)d_in[10];
  const float* W_gate = (const float*)d_in[11];
  const float* b_gate = (const float*)d_in[12];
  const float* W_dec  = (const float*)d_in[13];
  const float* b_dec  = (const float*)d_in[14];
  float* out = (float*)d_out;

  char* p = (char*)d_ws;
  u16* A_hi = (u16*)p; p += (size_t)NP * NP * 2;
  u16* A_md = (u16*)p; p += (size_t)NP * NP * 2;
  u16* A_lo = (u16*)p; p += (size_t)NP * NP * 2;
  u16* z_hi = (u16*)p; p += (size_t)4096 * NP * 2;
  u16* z_md = (u16*)p; p += (size_t)4096 * NP * 2;
  u16* z_lo = (u16*)p; p += (size_t)4096 * NP * 2;
  u16* h_hi = (u16*)p; p += (size_t)4096 * NP * 2;
  u16* h_md = (u16*)p; p += (size_t)4096 * NP * 2;
  u16* h_lo = (u16*)p; p += (size_t)4096 * NP * 2;
  float* Wf = (float*)p; p += 256 * 4;
  float* bfold = (float*)p; p += 64 * 4;

  k_prep<<<401, 256, 0, stream>>>(A, W_obs, b_obs, W_gate, A_hi, A_md, A_lo, Wf, bfold);
  k_main<<<NB, 512, 0, stream>>>(x_seq, obs, W_enc, b_enc, ln_g, ln_b,
                                 W_obs, b_obs, W_gate, b_gate, W_dec, b_dec,
                                 W_gc1, W_gc2, Wf, bfold,
                                 A_hi, A_md, A_lo,
                                 z_hi, z_md, z_lo, h_hi, h_md, h_lo, out);
  (void)in_sizes; (void)n_in; (void)out_size; (void)ws_size;
}